// Round 3
// baseline (111.988 us; speedup 1.0000x reference)
//
#include <hip/hip_runtime.h>
#include <hip/hip_bf16.h>

// JPEG 8x8 block DCT + quantization.
// image: [16,1,1024,1024] fp32; quality_factor: [16] fp32
// out:   [16,64,128,128] fp32, channel = k*8+l, out = (C @ (blk-128) @ C^T) / (factor*Q)
//
// R6 == R4 resubmitted (three infra failures in a row; no counters yet, so no blind
// changes). Theory vs R3: stage-1 was latency-exposed — 64 live accumulators +
// 128-VGPR cap forced the compiler to serialize row loads ~2 deep, leaving HBM at
// ~50% while the kernel is BW-bound with exact-minimal traffic of 128 MiB:
//  - Load ALL 16 dwordx4 up front as one burst (16 KiB MLP/wave, one latency/wave).
//  - Fuse stage1+stage2 per DCT row k: live set = r[8][8] (64) + tk[8] (8) instead
//    of tmp[8][8] (64) + load pipeline. FMA order identical to R3 -> bit-identical.
//  - LDS ping-pong transpose epilogue unchanged (verified in R3): 16 ld + 16 st
//    VMEM per thread, all float4, fully coalesced.

#define BS 8
#define HPIX 1024
#define WPIX 1024
#define HB (HPIX / BS)   // 128
#define WB (WPIX / BS)   // 128
#define BATCH 16

// Orthonormal DCT-II matrix C[k][n] = f_k * cos(pi*(2n+1)*k/16), fp32-rounded.
constexpr float DCT[8][8] = {
  { 0.35355339059327373f,  0.35355339059327373f,  0.35355339059327373f,  0.35355339059327373f,
    0.35355339059327373f,  0.35355339059327373f,  0.35355339059327373f,  0.35355339059327373f },
  { 0.49039264020161522f,  0.41573480615127262f,  0.27778511650980114f,  0.09754516100806413f,
   -0.09754516100806413f, -0.27778511650980114f, -0.41573480615127262f, -0.49039264020161522f },
  { 0.46193976625564337f,  0.19134171618254492f, -0.19134171618254492f, -0.46193976625564337f,
   -0.46193976625564337f, -0.19134171618254492f,  0.19134171618254492f,  0.46193976625564337f },
  { 0.41573480615127262f, -0.09754516100806413f, -0.49039264020161522f, -0.27778511650980114f,
    0.27778511650980114f,  0.49039264020161522f,  0.09754516100806413f, -0.41573480615127262f },
  { 0.35355339059327373f, -0.35355339059327373f, -0.35355339059327373f,  0.35355339059327373f,
    0.35355339059327373f, -0.35355339059327373f, -0.35355339059327373f,  0.35355339059327373f },
  { 0.27778511650980114f, -0.49039264020161522f,  0.09754516100806413f,  0.41573480615127262f,
   -0.41573480615127262f, -0.09754516100806413f,  0.49039264020161522f, -0.27778511650980114f },
  { 0.19134171618254492f, -0.46193976625564337f,  0.46193976625564337f, -0.19134171618254492f,
   -0.19134171618254492f,  0.46193976625564337f, -0.46193976625564337f,  0.19134171618254492f },
  { 0.09754516100806413f, -0.27778511650980114f,  0.41573480615127262f, -0.49039264020161522f,
    0.49039264020161522f, -0.41573480615127262f,  0.27778511650980114f, -0.09754516100806413f },
};

// 1 / (LUMINANCE_QUANTIZATION_TABLE / 100) = 100 / table entry
constexpr float INVQ[8][8] = {
  { 6.25f,              9.09090909090909f,  10.0f,              6.25f,
    4.16666666666667f,  2.5f,               1.96078431372549f,  1.63934426229508f },
  { 8.33333333333333f,  8.33333333333333f,  7.14285714285714f,  5.26315789473684f,
    3.84615384615385f,  1.72413793103448f,  1.66666666666667f,  1.81818181818182f },
  { 7.14285714285714f,  7.69230769230769f,  6.25f,              4.16666666666667f,
    2.5f,               1.75438596491228f,  1.44927536231884f,  1.78571428571429f },
  { 7.14285714285714f,  5.88235294117647f,  4.54545454545455f,  3.44827586206897f,
    1.96078431372549f,  1.14942528735632f,  1.25f,              1.61290322580645f },
  { 5.55555555555556f,  4.54545454545455f,  2.70270270270270f,  1.78571428571429f,
    1.47058823529412f,  0.91743119266055f,  0.970873786407767f, 1.29870129870130f },
  { 4.16666666666667f,  2.77777777777778f,  1.81818181818182f,  1.5625f,
    1.23456790123457f,  0.961538461538462f, 0.884955752212389f, 1.08695652173913f },
  { 2.04081632653061f,  1.5625f,            1.28205128205128f,  1.14942528735632f,
    0.970873786407767f, 0.826446280991736f, 0.833333333333333f, 0.990099009900990f },
  { 1.38888888888889f,  1.08695652173913f,  1.05263157894737f,  1.02040816326531f,
    0.892857142857143f, 1.0f,               0.970873786407767f, 1.01010101010101f },
};

// WG = 256 threads = 2 consecutive block-rows (h0, h0+1) x 128 block-cols, one batch.
// Thread t: w = t&127, hsub = t>>7. Grid = 16 batches * 64 h-pairs = 1024 WGs.
__global__ __launch_bounds__(256, 4) void jpeg_dct_q_kernel(
    const float* __restrict__ img,
    const float* __restrict__ qf,
    float* __restrict__ out)
{
    // ping-pong staging: [buf][hsub][l][w]; 2*2*8*128*4B = 16 KB
    __shared__ float lds[2][2][8][WB];

    const int t = threadIdx.x;
    const int g = blockIdx.x;
    const int b = g >> 6;                 // batch
    const int h0 = (g & 63) << 1;         // first block-row of the pair
    const int w = t & (WB - 1);           // block col
    const int hsub = t >> 7;              // 0/1 within the pair
    const int h = h0 + hsub;

    const float* rowbase = img + ((size_t)b << 20) + (size_t)(h * BS) * WPIX + (size_t)(w * BS);

    // ---- Load burst: all 16 global_load_dwordx4 issued back-to-back ----
    float4 va[8], vb[8];
#pragma unroll
    for (int n = 0; n < 8; ++n) {
        const float4* p = reinterpret_cast<const float4*>(rowbase + n * WPIX);
        va[n] = p[0];
        vb[n] = p[1];
    }

    // Center pixels; r[n][m] lives in registers (fully unrolled indexing).
    float r[8][8];
#pragma unroll
    for (int n = 0; n < 8; ++n) {
        r[n][0] = va[n].x - 128.0f; r[n][1] = va[n].y - 128.0f;
        r[n][2] = va[n].z - 128.0f; r[n][3] = va[n].w - 128.0f;
        r[n][4] = vb[n].x - 128.0f; r[n][5] = vb[n].y - 128.0f;
        r[n][6] = vb[n].z - 128.0f; r[n][7] = vb[n].w - 128.0f;
    }

    // Quantization scale: factor = QF<50 ? 5000/QF : 200-2*QF
    const float q = qf[b];
    const float factor = (q < 50.0f) ? (5000.0f / q) : (200.0f - 2.0f * q);
    const float rf = 1.0f / factor;

    // Phase-2 (flush) thread mapping: thread t -> (p_hsub, p_l, 2 w-groups of 4)
    const int p_hsub = t >> 7;
    const int p_l = (t >> 4) & 7;
    const int p_g0 = t & 15;
    const size_t obatch = (size_t)b << 20;

    // Per DCT row k (fused stage1+stage2): tk[m] = sum_n C[k][n]*r[n][m] (same FMA
    // order as R3), then 8 channels -> LDS (ping-pong) -> float4 stores.
    // One barrier per k is sufficient: reads of buf at k precede the barrier at
    // k+1, which precedes the next write of that buf at k+2.
#pragma unroll
    for (int k = 0; k < 8; ++k) {
        const int buf = k & 1;

        float tk[8];
#pragma unroll
        for (int m = 0; m < 8; ++m)
            tk[m] = 0.0f;
#pragma unroll
        for (int n = 0; n < 8; ++n) {
            const float cf = DCT[k][n];   // constexpr -> immediate
#pragma unroll
            for (int m = 0; m < 8; ++m)
                tk[m] = fmaf(cf, r[n][m], tk[m]);
        }

#pragma unroll
        for (int l = 0; l < 8; ++l) {
            float s = 0.0f;
#pragma unroll
            for (int m = 0; m < 8; ++m)
                s = fmaf(DCT[l][m], tk[m], s);
            lds[buf][hsub][l][w] = s * rf * INVQ[k][l];
        }
        __syncthreads();
#pragma unroll
        for (int it = 0; it < 2; ++it) {
            const int grp = p_g0 + 16 * it;          // w-group: 4 consecutive w
            float4 v = *reinterpret_cast<const float4*>(&lds[buf][p_hsub][p_l][4 * grp]);
            float* dst = out + obatch + (size_t)(k * 8 + p_l) * (HB * WB)
                             + (size_t)(h0 + p_hsub) * WB + 4 * grp;
            *reinterpret_cast<float4*>(dst) = v;
        }
    }
}

extern "C" void kernel_launch(void* const* d_in, const int* in_sizes, int n_in,
                              void* d_out, int out_size, void* d_ws, size_t ws_size,
                              hipStream_t stream) {
    const float* img = (const float*)d_in[0];
    const float* qf  = (const float*)d_in[1];
    float* out = (float*)d_out;

    const int grid = BATCH * (HB / 2);   // 1024 WGs: one per (batch, block-row pair)
    const int block = 256;

    jpeg_dct_q_kernel<<<grid, block, 0, stream>>>(img, qf, out);
}

// Round 5
// 111.250 us; speedup vs baseline: 1.0066x; 1.0066x over previous
//
#include <hip/hip_runtime.h>
#include <hip/hip_bf16.h>

// JPEG 8x8 block DCT + quantization.
// image: [16,1,1024,1024] fp32; quality_factor: [16] fp32
// out:   [16,64,128,128] fp32, channel = k*8+l, out = (C @ (blk-128) @ C^T) / (factor*Q)
//
// R8 == R7 resubmitted (infra failure; no measurement). Theory vs R4 (measured
// kernel < 41.6us dispatch; harness 111.99us dominated by 2x ~42us re-poison
// fills): the epilogue's 8 __syncthreads each force a s_waitcnt vmcnt(0) drain of
// the 2 global stores -> 8 exposed store latencies per wave vs the 21us BW floor.
//  - Wave-private LDS transpose: wave w owns (hsub=w>>1, wcol in [64*(w&1), +64)).
//    Each wave writes its 8x64 tile to its own 2KB LDS region and reads it back
//    as float4 rows WITHIN the wave. Same-wave DS ordering needs only lgkmcnt
//    (compiler-inserted) -> ALL barriers deleted -> no vmcnt(0) store drains;
//    stores pipeline across k under the next iteration's 128 FMAs.
//  - Load burst + fused stage1/stage2 per k unchanged (R4). FMA order identical
//    to verified R3 -> numerically identical. VMEM: 16 ldx4 + 16 stx4 unchanged.
//  - LDS writes: 8x ds_write_b32/lane/k, 2-way bank aliasing (free, m136);
//    reads: contiguous ds_read_b128, conflict-free. Ping-pong kept (WAR distance 2).

#define BS 8
#define HPIX 1024
#define WPIX 1024
#define HB (HPIX / BS)   // 128
#define WB (WPIX / BS)   // 128
#define BATCH 16

// Orthonormal DCT-II matrix C[k][n] = f_k * cos(pi*(2n+1)*k/16), fp32-rounded.
constexpr float DCT[8][8] = {
  { 0.35355339059327373f,  0.35355339059327373f,  0.35355339059327373f,  0.35355339059327373f,
    0.35355339059327373f,  0.35355339059327373f,  0.35355339059327373f,  0.35355339059327373f },
  { 0.49039264020161522f,  0.41573480615127262f,  0.27778511650980114f,  0.09754516100806413f,
   -0.09754516100806413f, -0.27778511650980114f, -0.41573480615127262f, -0.49039264020161522f },
  { 0.46193976625564337f,  0.19134171618254492f, -0.19134171618254492f, -0.46193976625564337f,
   -0.46193976625564337f, -0.19134171618254492f,  0.19134171618254492f,  0.46193976625564337f },
  { 0.41573480615127262f, -0.09754516100806413f, -0.49039264020161522f, -0.27778511650980114f,
    0.27778511650980114f,  0.49039264020161522f,  0.09754516100806413f, -0.41573480615127262f },
  { 0.35355339059327373f, -0.35355339059327373f, -0.35355339059327373f,  0.35355339059327373f,
    0.35355339059327373f, -0.35355339059327373f, -0.35355339059327373f,  0.35355339059327373f },
  { 0.27778511650980114f, -0.49039264020161522f,  0.09754516100806413f,  0.41573480615127262f,
   -0.41573480615127262f, -0.09754516100806413f,  0.49039264020161522f, -0.27778511650980114f },
  { 0.19134171618254492f, -0.46193976625564337f,  0.46193976625564337f, -0.19134171618254492f,
   -0.19134171618254492f,  0.46193976625564337f, -0.46193976625564337f,  0.19134171618254492f },
  { 0.09754516100806413f, -0.27778511650980114f,  0.41573480615127262f, -0.49039264020161522f,
    0.49039264020161522f, -0.41573480615127262f,  0.27778511650980114f, -0.09754516100806413f },
};

// 1 / (LUMINANCE_QUANTIZATION_TABLE / 100) = 100 / table entry
constexpr float INVQ[8][8] = {
  { 6.25f,              9.09090909090909f,  10.0f,              6.25f,
    4.16666666666667f,  2.5f,               1.96078431372549f,  1.63934426229508f },
  { 8.33333333333333f,  8.33333333333333f,  7.14285714285714f,  5.26315789473684f,
    3.84615384615385f,  1.72413793103448f,  1.66666666666667f,  1.81818181818182f },
  { 7.14285714285714f,  7.69230769230769f,  6.25f,              4.16666666666667f,
    2.5f,               1.75438596491228f,  1.44927536231884f,  1.78571428571429f },
  { 7.14285714285714f,  5.88235294117647f,  4.54545454545455f,  3.44827586206897f,
    1.96078431372549f,  1.14942528735632f,  1.25f,              1.61290322580645f },
  { 5.55555555555556f,  4.54545454545455f,  2.70270270270270f,  1.78571428571429f,
    1.47058823529412f,  0.91743119266055f,  0.970873786407767f, 1.29870129870130f },
  { 4.16666666666667f,  2.77777777777778f,  1.81818181818182f,  1.5625f,
    1.23456790123457f,  0.961538461538462f, 0.884955752212389f, 1.08695652173913f },
  { 2.04081632653061f,  1.5625f,            1.28205128205128f,  1.14942528735632f,
    0.970873786407767f, 0.826446280991736f, 0.833333333333333f, 0.990099009900990f },
  { 1.38888888888889f,  1.08695652173913f,  1.05263157894737f,  1.02040816326531f,
    0.892857142857143f, 1.0f,               0.970873786407767f, 1.01010101010101f },
};

// WG = 256 threads = 2 consecutive block-rows (h0, h0+1) x 128 block-cols, one batch.
// Wave wv (= t>>6): hsub = wv>>1, block-col range [64*(wv&1), 64*(wv&1)+64).
// Grid = 16 batches * 64 h-pairs = 1024 WGs (exactly 4 WGs/CU, all resident).
__global__ __launch_bounds__(256, 4) void jpeg_dct_q_kernel(
    const float* __restrict__ img,
    const float* __restrict__ qf,
    float* __restrict__ out)
{
    // Wave-private ping-pong staging: [wave][buf][l][w64]; 4*2*8*64*4B = 16 KB
    __shared__ float lds[4][2][8][64];

    const int t = threadIdx.x;
    const int lane = t & 63;
    const int wv = t >> 6;
    const int g = blockIdx.x;
    const int b = g >> 6;                 // batch
    const int h0 = (g & 63) << 1;         // first block-row of the pair
    const int hsub = wv >> 1;             // 0/1 within the pair
    const int wbase = (wv & 1) << 6;      // 0 or 64
    const int w = wbase + lane;           // block col (same global map as R3/R4)
    const int h = h0 + hsub;

    const float* rowbase = img + ((size_t)b << 20) + (size_t)(h * BS) * WPIX + (size_t)(w * BS);

    // ---- Load burst: all 16 global_load_dwordx4 issued back-to-back ----
    float4 va[8], vb[8];
#pragma unroll
    for (int n = 0; n < 8; ++n) {
        const float4* p = reinterpret_cast<const float4*>(rowbase + n * WPIX);
        va[n] = p[0];
        vb[n] = p[1];
    }

    // Center pixels; r[n][m] lives in registers (fully unrolled indexing).
    float r[8][8];
#pragma unroll
    for (int n = 0; n < 8; ++n) {
        r[n][0] = va[n].x - 128.0f; r[n][1] = va[n].y - 128.0f;
        r[n][2] = va[n].z - 128.0f; r[n][3] = va[n].w - 128.0f;
        r[n][4] = vb[n].x - 128.0f; r[n][5] = vb[n].y - 128.0f;
        r[n][6] = vb[n].z - 128.0f; r[n][7] = vb[n].w - 128.0f;
    }

    // Quantization scale: factor = QF<50 ? 5000/QF : 200-2*QF
    const float q = qf[b];
    const float factor = (q < 50.0f) ? (5000.0f / q) : (200.0f - 2.0f * q);
    const float rf = 1.0f / factor;

    // Phase-2 (flush) mapping, within-wave: lane -> (row0 = lane>>4, chunk = lane&15).
    // Store rows row0 and row0+4 per k; each store = 16 lanes x 16B = 256B/row, coalesced.
    const int row0 = lane >> 4;           // 0..3
    const int chunk = lane & 15;          // w-group of 4 within this wave's 64 cols
    const size_t obatch = (size_t)b << 20;

    // Per DCT row k (fused stage1+stage2): tk[m] = sum_n C[k][n]*r[n][m] (same FMA
    // order as R3), then 8 channels -> wave-private LDS -> float4 stores.
    // No __syncthreads anywhere: producer and consumer lanes are in the SAME wave,
    // ordered by compiler-inserted lgkmcnt waits. Ping-pong gives WAR distance 2.
#pragma unroll
    for (int k = 0; k < 8; ++k) {
        const int buf = k & 1;

        float tk[8];
#pragma unroll
        for (int m = 0; m < 8; ++m)
            tk[m] = 0.0f;
#pragma unroll
        for (int n = 0; n < 8; ++n) {
            const float cf = DCT[k][n];   // constexpr -> immediate
#pragma unroll
            for (int m = 0; m < 8; ++m)
                tk[m] = fmaf(cf, r[n][m], tk[m]);
        }

#pragma unroll
        for (int l = 0; l < 8; ++l) {
            float s = 0.0f;
#pragma unroll
            for (int m = 0; m < 8; ++m)
                s = fmaf(DCT[l][m], tk[m], s);
            lds[wv][buf][l][lane] = s * rf * INVQ[k][l];
        }

#pragma unroll
        for (int it = 0; it < 2; ++it) {
            const int row = row0 + 4 * it;           // channel l within this k
            float4 v = *reinterpret_cast<const float4*>(&lds[wv][buf][row][4 * chunk]);
            float* dst = out + obatch + (size_t)(k * 8 + row) * (HB * WB)
                             + (size_t)h * WB + wbase + 4 * chunk;
            *reinterpret_cast<float4*>(dst) = v;
        }
    }
}

extern "C" void kernel_launch(void* const* d_in, const int* in_sizes, int n_in,
                              void* d_out, int out_size, void* d_ws, size_t ws_size,
                              hipStream_t stream) {
    const float* img = (const float*)d_in[0];
    const float* qf  = (const float*)d_in[1];
    float* out = (float*)d_out;

    const int grid = BATCH * (HB / 2);   // 1024 WGs: one per (batch, block-row pair)
    const int block = 256;

    jpeg_dct_q_kernel<<<grid, block, 0, stream>>>(img, qf, out);
}